// Round 2
// baseline (171.829 us; speedup 1.0000x reference)
//
#include <hip/hip_runtime.h>
#include <stdint.h>

#define BB 64
#define LL 512
#define DD 300
#define CC 128
#define TCH 8
#define TOK (LL / TCH)

// ---------------------------------------------------------------------------
// Kernel 1: weighted embedding gather (all f32).
//   G[b][kk][d] = sum_t u_k[t] * embed[x[b,t]][d]
// u_k[t] = sum of wk[l] over valid windows covering token t (<=5 terms),
// recomputed per block. Grid: (b, token-chunk) = 64*8 blocks of 128 threads.
// Each thread owns float2 d-slots {tid, 128+tid(<150)}; rows read coalesced
// (1200 B/row). Partials land in G via f32 atomicAdd (8 contributors/addr).
// ---------------------------------------------------------------------------
__global__ __launch_bounds__(128) void k_gather(
    const int* __restrict__ x, const float* __restrict__ embed,
    const float* __restrict__ w3, const float* __restrict__ w4,
    const float* __restrict__ w5, float* __restrict__ G) {
  const int b = blockIdx.x >> 3;
  const int tc = blockIdx.x & 7;
  const int t0 = tc * TOK;
  const int tid = threadIdx.x;

  __shared__ int sx[TOK];
  __shared__ float su[3][TOK];

  if (tid < TOK) {
    const int t = t0 + tid;
    sx[tid] = x[b * LL + t];
    const float* ws[3] = {w3, w4, w5};
#pragma unroll
    for (int kk = 0; kk < 3; ++kk) {
      const int k = kk + 3;
      int lo = t - k + 1; if (lo < 0) lo = 0;
      int hi = t; const int lim = LL - k - 1; if (hi > lim) hi = lim;
      float s = 0.f;
      for (int l = lo; l <= hi; ++l) s += ws[kk][l];
      su[kk][tid] = s;
    }
  }
  __syncthreads();

  float a0x = 0.f, a0y = 0.f, a1x = 0.f, a1y = 0.f, a2x = 0.f, a2y = 0.f;
  float c0x = 0.f, c0y = 0.f, c1x = 0.f, c1y = 0.f, c2x = 0.f, c2y = 0.f;
  const bool tail = tid < (DD / 2 - 128);  // float2 slots 128..149 -> 22 lanes

#pragma unroll 4
  for (int i = 0; i < TOK; ++i) {
    const float2* rp = (const float2*)(embed + (size_t)sx[i] * DD);
    const float2 v = rp[tid];
    const float w0 = su[0][i], w1 = su[1][i], w2 = su[2][i];
    a0x += w0 * v.x; a0y += w0 * v.y;
    a1x += w1 * v.x; a1y += w1 * v.y;
    a2x += w2 * v.x; a2y += w2 * v.y;
    if (tail) {
      const float2 v2 = rp[128 + tid];
      c0x += w0 * v2.x; c0y += w0 * v2.y;
      c1x += w1 * v2.x; c1y += w1 * v2.y;
      c2x += w2 * v2.x; c2y += w2 * v2.y;
    }
  }

  float* Gb = G + b * (3 * DD);
  const int d0 = 2 * tid;
  atomicAdd(&Gb[0 * DD + d0], a0x); atomicAdd(&Gb[0 * DD + d0 + 1], a0y);
  atomicAdd(&Gb[1 * DD + d0], a1x); atomicAdd(&Gb[1 * DD + d0 + 1], a1y);
  atomicAdd(&Gb[2 * DD + d0], a2x); atomicAdd(&Gb[2 * DD + d0 + 1], a2y);
  if (tail) {
    const int d1 = 2 * (128 + tid);
    atomicAdd(&Gb[0 * DD + d1], c0x); atomicAdd(&Gb[0 * DD + d1 + 1], c0y);
    atomicAdd(&Gb[1 * DD + d1], c1x); atomicAdd(&Gb[1 * DD + d1 + 1], c1y);
    atomicAdd(&Gb[2 * DD + d1], c2x); atomicAdd(&Gb[2 * DD + d1 + 1], c2y);
  }
}

// ---------------------------------------------------------------------------
// Kernel 2: per-(b,kk) sim head.
//   hT[(kk*128 + c')*64 + b] = <conv_w[c',:], G[b,kk,:]> + conv_b[c']*S_k + bk
// One block per (b,kk) = 192 blocks of 256 threads. G row staged in LDS; each
// wave computes 32 c' outputs via lane-parallel dot + shfl reduction
// (coalesced conv_w reads, no lane scatter). hT stored j-major so k_fc reads
// it coalesced over b.
// ---------------------------------------------------------------------------
__global__ __launch_bounds__(256) void k_sim(
    const float* __restrict__ G, const float* __restrict__ conv_w,
    const float* __restrict__ conv_b,
    const float* __restrict__ w3, const float* __restrict__ b3,
    const float* __restrict__ w4, const float* __restrict__ b4,
    const float* __restrict__ w5, const float* __restrict__ b5,
    float* __restrict__ hT) {
  const int blk = blockIdx.x;  // 192 = 64 b * 3 kk
  const int b = blk / 3;
  const int kk = blk % 3;
  const int tid = threadIdx.x;
  const int lane = tid & 63;
  const int wid = tid >> 6;

  __shared__ __align__(16) float sG[DD];
  __shared__ float red[256];

  const float* wk = (kk == 0) ? w3 : ((kk == 1) ? w4 : w5);
  const float* bk = (kk == 0) ? b3 : ((kk == 1) ? b4 : b5);
  const int len = LL - (kk + 3);

  float s = 0.f;
  for (int j = tid; j < len; j += 256) s += wk[j];
  red[tid] = s;
  for (int j = tid; j < DD; j += 256) sG[j] = G[(b * 3 + kk) * DD + j];
  __syncthreads();
  for (int off = 128; off >= 1; off >>= 1) {
    if (tid < off) red[tid] += red[tid + off];
    __syncthreads();
  }
  const float Sk = red[0];
  const float bkv = bk[0];
  const float2* sG2 = (const float2*)sG;

  for (int m = 0; m < 32; ++m) {
    const int cp = wid * 32 + m;
    const float2* cwp = (const float2*)(conv_w + cp * DD);  // 150 float2
    float acc = 0.f;
    {
      const float2 v = cwp[lane];
      const float2 g = sG2[lane];
      acc += v.x * g.x + v.y * g.y;
    }
    {
      const float2 v = cwp[lane + 64];
      const float2 g = sG2[lane + 64];
      acc += v.x * g.x + v.y * g.y;
    }
    if (lane < 22) {
      const float2 v = cwp[lane + 128];
      const float2 g = sG2[lane + 128];
      acc += v.x * g.x + v.y * g.y;
    }
#pragma unroll
    for (int off = 32; off >= 1; off >>= 1) acc += __shfl_down(acc, off, 64);
    if (lane == 0) {
      hT[(kk * CC + cp) * BB + b] = acc + conv_b[cp] * Sk + bkv;
    }
  }
}

// ---------------------------------------------------------------------------
// Kernel 3: final FC.  out[b,c] = sum_j fcw[c,j]*hT[j,b] + fcb[c]
// Block per c (128 blocks), lane = b (64). fcw row is wave-uniform (float4
// scalar-ish loads), hT loads coalesced (256 B per j).
// ---------------------------------------------------------------------------
__global__ __launch_bounds__(64) void k_fc(
    const float* __restrict__ hT, const float* __restrict__ fcw,
    const float* __restrict__ fcb, float* __restrict__ out) {
  const int c = blockIdx.x;
  const int lane = threadIdx.x;
  const float4* row4 = (const float4*)(fcw + c * (3 * CC));  // 96 float4
  float acc0 = 0.f, acc1 = 0.f, acc2 = 0.f, acc3 = 0.f;
#pragma unroll 4
  for (int j4 = 0; j4 < (3 * CC) / 4; ++j4) {
    const float4 w = row4[j4];
    const int j = 4 * j4;
    acc0 += w.x * hT[(j + 0) * BB + lane];
    acc1 += w.y * hT[(j + 1) * BB + lane];
    acc2 += w.z * hT[(j + 2) * BB + lane];
    acc3 += w.w * hT[(j + 3) * BB + lane];
  }
  out[lane * CC + c] = (acc0 + acc1) + (acc2 + acc3) + fcb[c];
}

// ---------------------------------------------------------------------------
extern "C" void kernel_launch(void* const* d_in, const int* in_sizes, int n_in,
                              void* d_out, int out_size, void* d_ws,
                              size_t ws_size, hipStream_t stream) {
  const int* x = (const int*)d_in[0];
  const float* embed = (const float*)d_in[1];
  const float* conv_w = (const float*)d_in[2];
  const float* conv_b = (const float*)d_in[3];
  const float* fc3w = (const float*)d_in[4];
  const float* fc3b = (const float*)d_in[5];
  const float* fc4w = (const float*)d_in[6];
  const float* fc4b = (const float*)d_in[7];
  const float* fc5w = (const float*)d_in[8];
  const float* fc5b = (const float*)d_in[9];
  const float* fcw = (const float*)d_in[10];
  const float* fcb = (const float*)d_in[11];

  float* G = (float*)d_ws;          // 64*3*300 = 57600 f32
  float* hT = G + BB * 3 * DD;      // 384*64  = 24576 f32  (total ws ~329 KB)

  hipMemsetAsync(G, 0, (size_t)BB * 3 * DD * sizeof(float), stream);
  k_gather<<<dim3(BB * TCH), dim3(128), 0, stream>>>(x, embed, fc3w, fc4w,
                                                     fc5w, G);
  k_sim<<<dim3(BB * 3), dim3(256), 0, stream>>>(G, conv_w, conv_b, fc3w, fc3b,
                                                fc4w, fc4b, fc5w, fc5b, hT);
  k_fc<<<dim3(CC), dim3(64), 0, stream>>>(hT, fcw, fcb, (float*)d_out);
}